// Round 4
// baseline (765.321 us; speedup 1.0000x reference)
//
#include <hip/hip_runtime.h>
#include <hip/hip_bf16.h>

typedef __attribute__((ext_vector_type(8))) __bf16 bf16x8;
typedef __attribute__((ext_vector_type(4))) float f32x4;
typedef unsigned long long u64;

#define MFMA16(a, b, c) __builtin_amdgcn_mfma_f32_16x16x32_bf16(a, b, c, 0, 0, 0)

__device__ __forceinline__ void gload_lds16(const void* g, void* l) {
  __builtin_amdgcn_global_load_lds((const __attribute__((address_space(1))) void*)g,
                                   (__attribute__((address_space(3))) void*)l, 16, 0, 0);
}

// ---------------------------------------------------------------------------
// Kernel 1: convert q/k/v f32 -> bf16.  query goes into cat[:,1024:2048].
// ---------------------------------------------------------------------------
__global__ __launch_bounds__(256) void convert_qkv(
    const float* __restrict__ q, const float* __restrict__ k, const float* __restrict__ v,
    __bf16* __restrict__ cat, __bf16* __restrict__ keyb, __bf16* __restrict__ valueb) {
  const int z = blockIdx.y;
  const size_t idx = ((size_t)blockIdx.x * 256 + threadIdx.x) * 8;
  const float* src = (z == 0) ? q : (z == 1 ? k : v);
  float4 a = *(const float4*)(src + idx);
  float4 c = *(const float4*)(src + idx + 4);
  bf16x8 o;
  o[0] = (__bf16)a.x; o[1] = (__bf16)a.y; o[2] = (__bf16)a.z; o[3] = (__bf16)a.w;
  o[4] = (__bf16)c.x; o[5] = (__bf16)c.y; o[6] = (__bf16)c.z; o[7] = (__bf16)c.w;
  __bf16* dst;
  if (z == 0) {
    size_t row = idx >> 10, col = idx & 1023;
    dst = cat + row * 2048 + 1024 + col;
  } else {
    dst = (z == 1 ? keyb : valueb) + idx;
  }
  *(bf16x8*)dst = o;
}

// ---------------------------------------------------------------------------
// Kernel 2: transpose-convert weights  W[K][N=1024] f32  ->  WT[N][K] bf16
// ---------------------------------------------------------------------------
__global__ __launch_bounds__(256) void transpose_w(
    const float* __restrict__ Wq, const float* __restrict__ Wk,
    const float* __restrict__ Wv, const float* __restrict__ Wf,
    __bf16* __restrict__ WqT, __bf16* __restrict__ WkT,
    __bf16* __restrict__ WvT, __bf16* __restrict__ WfT) {
  const int z = blockIdx.z;
  const float* W; __bf16* WT; int K;
  if (z == 0)      { W = Wq; WT = WqT; K = 1024; }
  else if (z == 1) { W = Wk; WT = WkT; K = 1024; }
  else if (z == 2) { W = Wv; WT = WvT; K = 1024; }
  else             { W = Wf; WT = WfT; K = 2048; }
  const int y0 = blockIdx.y * 32;      // k block
  if (y0 >= K) return;
  const int x0 = blockIdx.x * 32;      // n block
  __shared__ float tile[32][33];
  const int tx = threadIdx.x & 31, ty = threadIdx.x >> 5;
#pragma unroll
  for (int i = 0; i < 4; ++i)
    tile[ty + i * 8][tx] = W[(size_t)(y0 + ty + i * 8) * 1024 + x0 + tx];
  __syncthreads();
#pragma unroll
  for (int i = 0; i < 4; ++i)
    WT[(size_t)(x0 + ty + i * 8) * K + y0 + tx] = (__bf16)tile[tx][ty + i * 8];
}

// ---------------------------------------------------------------------------
// Kernel 3: pack mask int32 -> 1 bit (bit j of word w = mask[w*64+j]).
// Word index = (hb*1024 + row)*16 + chunk; bit = within-chunk column.
// ---------------------------------------------------------------------------
__global__ __launch_bounds__(256) void pack_mask(
    const int* __restrict__ m, u64* __restrict__ bits) {
  const int lane = threadIdx.x & 63;
  const size_t wv0 = (((size_t)blockIdx.x * 256) + threadIdx.x) >> 6;
  const size_t stride = ((size_t)gridDim.x * 256) >> 6;
  const size_t nw = (size_t)1024 * 1024;  // 64M / 64
  for (size_t w = wv0; w < nw; w += stride) {
    int x = m[(w << 6) + lane];
    u64 b = __ballot(x != 0);
    if (lane == 0) bits[w] = b;
  }
}

// ---------------------------------------------------------------------------
// Kernel 4: unified 128x128 GEMM, 2-phase double-buffered LDS pipeline.
// z=0..2: Q/K/V projections (bf16 out). z=3: final out = cat@Wf + bf + query.
// ---------------------------------------------------------------------------
__global__ __launch_bounds__(256) void gemm_all(
    const __bf16* __restrict__ cat, const __bf16* __restrict__ keyb,
    const __bf16* __restrict__ valueb,
    const __bf16* __restrict__ WqT, const __bf16* __restrict__ WkT,
    const __bf16* __restrict__ WvT, const __bf16* __restrict__ WfT,
    const float* __restrict__ bq, const float* __restrict__ bk,
    const float* __restrict__ bv, const float* __restrict__ bfw,
    __bf16* __restrict__ Qb, __bf16* __restrict__ Kb, __bf16* __restrict__ Vb,
    float* __restrict__ outp, const float* __restrict__ resid, int zbase) {
  __shared__ __bf16 Alds[2][128 * 32];
  __shared__ __bf16 Blds[2][128 * 32];
  const int z = blockIdx.z + zbase;
  const __bf16* A; int lda; const __bf16* BT; int ldb; const float* bias;
  __bf16* dstb = nullptr; int K;
  if (z == 0)      { A = cat + 1024; lda = 2048; BT = WqT; ldb = 1024; bias = bq; dstb = Qb; K = 1024; }
  else if (z == 1) { A = keyb;   lda = 1024; BT = WkT; ldb = 1024; bias = bk; dstb = Kb; K = 1024; }
  else if (z == 2) { A = valueb; lda = 1024; BT = WvT; ldb = 1024; bias = bv; dstb = Vb; K = 1024; }
  else             { A = cat;    lda = 2048; BT = WfT; ldb = 2048; bias = bfw; K = 2048; }

  const int tid = threadIdx.x;
  const int lane = tid & 63, w = tid >> 6;
  const int l15 = lane & 15, lg = lane >> 4;
  const int brow = blockIdx.y * 128, bcol = blockIdx.x * 128;
  const int wr = w >> 1, wc = w & 1;
  f32x4 acc[4][4] = {};

  const int s0 = w * 2, s1 = w * 2 + 1;
  const int srow0 = s0 * 16 + (lane >> 2);
  const int srow1 = s1 * 16 + (lane >> 2);
  const int scol = (lane & 3) * 8;

  const __bf16* a0 = A + (size_t)(brow + srow0) * lda + scol;
  const __bf16* a1 = A + (size_t)(brow + srow1) * lda + scol;
  const __bf16* b0 = BT + (size_t)(bcol + srow0) * ldb + scol;
  const __bf16* b1 = BT + (size_t)(bcol + srow1) * ldb + scol;

  // prologue: stage tile 0 into buf 0
  gload_lds16(a0, &Alds[0][s0 * 512]);
  gload_lds16(a1, &Alds[0][s1 * 512]);
  gload_lds16(b0, &Blds[0][s0 * 512]);
  gload_lds16(b1, &Blds[0][s1 * 512]);
  __syncthreads();

  int cur = 0;
  for (int k0 = 0; k0 < K; k0 += 32) {
    // stage next tile into the other buffer (overlaps with MFMA below)
    if (k0 + 32 < K) {
      const int nb = cur ^ 1, kn = k0 + 32;
      gload_lds16(a0 + kn, &Alds[nb][s0 * 512]);
      gload_lds16(a1 + kn, &Alds[nb][s1 * 512]);
      gload_lds16(b0 + kn, &Blds[nb][s0 * 512]);
      gload_lds16(b1 + kn, &Blds[nb][s1 * 512]);
    }
    bf16x8 af[4], bfr[4];
#pragma unroll
    for (int rt = 0; rt < 4; ++rt)
      af[rt] = *(const bf16x8*)(&Alds[cur][(wr * 64 + rt * 16 + l15) * 32 + lg * 8]);
#pragma unroll
    for (int ct = 0; ct < 4; ++ct)
      bfr[ct] = *(const bf16x8*)(&Blds[cur][(wc * 64 + ct * 16 + l15) * 32 + lg * 8]);
#pragma unroll
    for (int rt = 0; rt < 4; ++rt)
#pragma unroll
      for (int ct = 0; ct < 4; ++ct)
        acc[rt][ct] = MFMA16(af[rt], bfr[ct], acc[rt][ct]);
    __syncthreads();  // drains vmcnt (next tile resident) + all reads of cur done
    cur ^= 1;
  }

#pragma unroll
  for (int rt = 0; rt < 4; ++rt)
#pragma unroll
    for (int ct = 0; ct < 4; ++ct) {
      const int col = bcol + wc * 64 + ct * 16 + l15;
#pragma unroll
      for (int r = 0; r < 4; ++r) {
        const int row = brow + wr * 64 + rt * 16 + lg * 4 + r;
        float vv = acc[rt][ct][r] + bias[col];
        if (z < 3) {
          dstb[(size_t)row * 1024 + col] = (__bf16)vv;
        } else {
          outp[(size_t)row * 1024 + col] = vv + resid[(size_t)row * 1024 + col];
        }
      }
    }
}

// ---------------------------------------------------------------------------
// Kernel 5: fused attention.  One workgroup = one (h,b) x 32 q-rows.
// Packed-bit mask; single barrier per KV chunk; XCD-swizzled blocks.
// ---------------------------------------------------------------------------
__global__ __launch_bounds__(256) void attn_kernel(
    const __bf16* __restrict__ Qb, const __bf16* __restrict__ Kb,
    const __bf16* __restrict__ Vb, const u64* __restrict__ mbits,
    const float* __restrict__ qmask, float* __restrict__ attn_out,
    __bf16* __restrict__ cat) {
  __shared__ __bf16 e_lds[32][1032];   // unnormalized exp(s); chunk ch owns cols ch*64..+63
  __shared__ __bf16 vt[64][72];        // V chunk transposed [d][j]; rows wave-private
  __shared__ float l_sh[4][32];
  __shared__ float srow[32];

  const int tid = threadIdx.x;
  const int lane = tid & 63, w = tid >> 6;
  const int l15 = lane & 15, lg = lane >> 4;
  // XCD-aware swizzle: 2048 blocks = 8 XCD * 256; each XCD gets 8 contiguous (h,b)
  const int wg_raw = blockIdx.x;
  const int wg = (wg_raw & 7) * 256 + (wg_raw >> 3);
  const int hb = wg >> 5, rb = wg & 31;
  const int h = hb >> 2, b = hb & 3;
  const int qbase = rb * 32;
  const int shift = w * 16 + l15;      // within-chunk column = mask bit index
  const float C = 0.18033688011112042f;  // log2(e) / 8

  const u64* mrow_bits = mbits + ((size_t)hb * 1024 + qbase) * 16;

  // preload Q fragments (rows qbase..qbase+31, this head's 64 dims)
  bf16x8 aq[2][2];
#pragma unroll
  for (int rt = 0; rt < 2; ++rt)
#pragma unroll
    for (int kk = 0; kk < 2; ++kk)
      aq[rt][kk] = *(const bf16x8*)(Qb + (size_t)(b * 1024 + qbase + rt * 16 + l15) * 1024 +
                                    h * 64 + kk * 32 + lg * 8);

  f32x4 acc_o[2] = {};
  float lp[2][4] = {};

  for (int ch = 0; ch < 16; ++ch) {
    const int jbase = ch * 64;
    // ---- stage V chunk transposed: vt[d][j]; wave w writes/reads ONLY rows w*16..+15
    {
      const int j = lane;
      const __bf16* vsrc = Vb + (size_t)(b * 1024 + jbase + j) * 1024 + h * 64 + w * 16;
      bf16x8 v0 = *(const bf16x8*)(vsrc);
      bf16x8 v1 = *(const bf16x8*)(vsrc + 8);
#pragma unroll
      for (int i = 0; i < 8; ++i) vt[w * 16 + i][j] = v0[i];
#pragma unroll
      for (int i = 0; i < 8; ++i) vt[w * 16 + 8 + i][j] = v1[i];
    }
    // ---- S = Q K^T for this wave's 16 columns; mask from packed bits
    const int jcol = jbase + w * 16;
    bf16x8 bk0 = *(const bf16x8*)(Kb + (size_t)(b * 1024 + jcol + l15) * 1024 + h * 64 + lg * 8);
    bf16x8 bk1 = *(const bf16x8*)(Kb + (size_t)(b * 1024 + jcol + l15) * 1024 + h * 64 + 32 + lg * 8);
#pragma unroll
    for (int rt = 0; rt < 2; ++rt) {
      f32x4 s = {};
      s = MFMA16(aq[rt][0], bk0, s);
      s = MFMA16(aq[rt][1], bk1, s);
#pragma unroll
      for (int r = 0; r < 4; ++r) {
        u64 mw = mrow_bits[(size_t)(rt * 16 + lg * 4 + r) * 16 + ch];
        float e = ((mw >> shift) & 1) ? 0.f : exp2f(s[r] * C);
        lp[rt][r] += e;
        e_lds[rt * 16 + lg * 4 + r][jcol + l15] = (__bf16)e;
      }
    }
    __syncthreads();  // e_lds chunk columns visible to all waves
    // ---- PV: acc_o += e(32 x 64) @ V(64 x 64d); wave w owns d-cols w*16..+16
#pragma unroll
    for (int kk = 0; kk < 2; ++kk) {
      bf16x8 bv = *(const bf16x8*)(&vt[w * 16 + l15][kk * 32 + lg * 8]);
#pragma unroll
      for (int rt = 0; rt < 2; ++rt) {
        bf16x8 ae = *(const bf16x8*)(&e_lds[rt * 16 + l15][jbase + kk * 32 + lg * 8]);
        acc_o[rt] = MFMA16(ae, bv, acc_o[rt]);
      }
    }
    // no second barrier: next chunk writes disjoint e_lds columns & wave-private vt rows
  }

  // ---- row-sum reduce: intra-16-lane, then cross-wave via LDS
#pragma unroll
  for (int rt = 0; rt < 2; ++rt)
#pragma unroll
    for (int r = 0; r < 4; ++r) {
      float v = lp[rt][r];
      v += __shfl_xor(v, 1);
      v += __shfl_xor(v, 2);
      v += __shfl_xor(v, 4);
      v += __shfl_xor(v, 8);
      if (l15 == 0) l_sh[w][rt * 16 + lg * 4 + r] = v;
    }
  __syncthreads();
  if (tid < 32) {
    float l = l_sh[0][tid] + l_sh[1][tid] + l_sh[2][tid] + l_sh[3][tid];
    float qm = qmask[b * 1024 + qbase + tid];
    srow[tid] = qm / l;
  }
  __syncthreads();

  // ---- write normalized attention (f32, coalesced float4)
  float* aout = attn_out + ((size_t)hb * 1024 + qbase) * 1024;
  for (int it = 0; it < 32; ++it) {
    int idx = it * 256 + tid;
    int row = idx >> 8;
    int c4 = (idx & 255) * 4;
    float sc = srow[row];
    float4 o;
    o.x = (float)e_lds[row][c4 + 0] * sc;
    o.y = (float)e_lds[row][c4 + 1] * sc;
    o.z = (float)e_lds[row][c4 + 2] * sc;
    o.w = (float)e_lds[row][c4 + 3] * sc;
    *(float4*)(aout + (size_t)row * 1024 + c4) = o;
  }

  // ---- write x into cat[:, 0:1024]  (layout b,i,h,d)
#pragma unroll
  for (int rt = 0; rt < 2; ++rt)
#pragma unroll
    for (int r = 0; r < 4; ++r) {
      const int rl = rt * 16 + lg * 4 + r;
      float v = acc_o[rt][r] * srow[rl];
      cat[(size_t)(b * 1024 + qbase + rl) * 2048 + h * 64 + w * 16 + l15] = (__bf16)v;
    }
}

// ---------------------------------------------------------------------------
extern "C" void kernel_launch(void* const* d_in, const int* in_sizes, int n_in,
                              void* d_out, int out_size, void* d_ws, size_t ws_size,
                              hipStream_t stream) {
  const float* query = (const float*)d_in[0];
  const float* key   = (const float*)d_in[1];
  const float* value = (const float*)d_in[2];
  const int*   mask  = (const int*)d_in[3];
  const float* qmask = (const float*)d_in[4];
  const float* Wq = (const float*)d_in[5];  const float* bq = (const float*)d_in[6];
  const float* Wk = (const float*)d_in[7];  const float* bk = (const float*)d_in[8];
  const float* Wv = (const float*)d_in[9];  const float* bv = (const float*)d_in[10];
  const float* Wf = (const float*)d_in[11]; const float* bfb = (const float*)d_in[12];

  float* out = (float*)d_out;
  float* attn_out = out + (size_t)4 * 1024 * 1024;

  char* ws = (char*)d_ws;
  const size_t MB = 1024 * 1024;
  __bf16* cat    = (__bf16*)(ws);             // 16 MB: [x | query] bf16, 4096x2048
  __bf16* keyb   = (__bf16*)(ws + 16 * MB);   // 8 MB
  __bf16* valueb = (__bf16*)(ws + 24 * MB);   // 8 MB
  __bf16* Qb     = (__bf16*)(ws + 32 * MB);   // 8 MB
  __bf16* Kb     = (__bf16*)(ws + 40 * MB);   // 8 MB
  __bf16* Vb     = (__bf16*)(ws + 48 * MB);   // 8 MB
  __bf16* WqT    = (__bf16*)(ws + 56 * MB);   // 2 MB
  __bf16* WkT    = (__bf16*)(ws + 58 * MB);   // 2 MB
  __bf16* WvT    = (__bf16*)(ws + 60 * MB);   // 2 MB
  __bf16* WfT    = (__bf16*)(ws + 62 * MB);   // 4 MB
  u64*    mbits  = (u64*)(ws + 66 * MB);      // 8 MB

  // 1) converts + mask pack
  convert_qkv<<<dim3(2048, 3), 256, 0, stream>>>(query, key, value, cat, keyb, valueb);
  transpose_w<<<dim3(32, 64, 4), 256, 0, stream>>>(Wq, Wk, Wv, Wf, WqT, WkT, WvT, WfT);
  pack_mask<<<dim3(2048), 256, 0, stream>>>(mask, mbits);

  // 2) Q/K/V projections fused in one launch (768 blocks = 3/CU)
  gemm_all<<<dim3(8, 32, 3), 256, 0, stream>>>(cat, keyb, valueb, WqT, WkT, WvT, WfT,
                                               bq, bk, bv, bfb, Qb, Kb, Vb, out, query, 0);

  // 3) fused attention (writes attn_out and cat[:,0:1024])
  attn_kernel<<<dim3(2048), 256, 0, stream>>>(Qb, Kb, Vb, mbits, qmask, attn_out, cat);

  // 4) final GEMM: out = cat @ Wf + bf + query  (f32 out)
  gemm_all<<<dim3(8, 32, 1), 256, 0, stream>>>(cat, keyb, valueb, WqT, WkT, WvT, WfT,
                                               bq, bk, bv, bfb, Qb, Kb, Vb, out, query, 3);
}